// Round 2
// baseline (877.789 us; speedup 1.0000x reference)
//
#include <hip/hip_runtime.h>

#define NN 100000
#define NE 3200000
#define NFEAT 256
#define HDIM 64
#define NCLASS 64
#define ALPHA 0.1f

// ---------------- CSR build ----------------

__global__ void init_nodes(int* __restrict__ deg, int* __restrict__ cursor, int n) {
    int i = blockIdx.x * blockDim.x + threadIdx.x;
    if (i < n) { deg[i] = 1; cursor[i] = 0; }   // deg starts at 1 for the self-loop
}

__global__ void count_deg(const int* __restrict__ ei, int* __restrict__ deg, int e) {
    int i = blockIdx.x * blockDim.x + threadIdx.x;
    if (i < e) atomicAdd(&deg[ei[NE + i]], 1);   // dst row
}

__global__ void calc_dinv(const int* __restrict__ deg, float* __restrict__ dinv, int n) {
    int i = blockIdx.x * blockDim.x + threadIdx.x;
    if (i < n) dinv[i] = rsqrtf((float)deg[i]);  // deg >= 1 always
}

// exclusive scan of cnt[i] = deg[i]-1 (edges only; self-loops are implicit)
// chunk = 1024 elements per block (256 threads x 4 contiguous)

__global__ void scan_block_sums(const int* __restrict__ deg, int* __restrict__ bsums, int n) {
    __shared__ int sm[256];
    int t = threadIdx.x;
    int base = blockIdx.x * 1024 + t * 4;
    int s = 0;
#pragma unroll
    for (int c = 0; c < 4; c++) { int idx = base + c; if (idx < n) s += deg[idx] - 1; }
    sm[t] = s; __syncthreads();
    for (int off = 128; off > 0; off >>= 1) {
        if (t < off) sm[t] += sm[t + off];
        __syncthreads();
    }
    if (t == 0) bsums[blockIdx.x] = sm[0];
}

__global__ void scan_bsums(int* __restrict__ bsums, int nb, int* __restrict__ rowptr, int n) {
    if (threadIdx.x == 0 && blockIdx.x == 0) {
        int run = 0;
        for (int i = 0; i < nb; i++) { int v = bsums[i]; bsums[i] = run; run += v; }
        rowptr[n] = run;   // == NE
    }
}

__global__ void scan_write_rowptr(const int* __restrict__ deg, const int* __restrict__ bsums,
                                  int* __restrict__ rowptr, int n) {
    __shared__ int sm[256];
    int t = threadIdx.x;
    int base = blockIdx.x * 1024 + t * 4;
    int c4[4];
    int s = 0;
#pragma unroll
    for (int c = 0; c < 4; c++) {
        int idx = base + c;
        c4[c] = (idx < n) ? deg[idx] - 1 : 0;
        s += c4[c];
    }
    sm[t] = s; __syncthreads();
    for (int off = 1; off < 256; off <<= 1) {
        int v = 0;
        if (t >= off) v = sm[t - off];
        __syncthreads();
        if (t >= off) sm[t] += v;
        __syncthreads();
    }
    int excl = sm[t] - s + bsums[blockIdx.x];
#pragma unroll
    for (int c = 0; c < 4; c++) {
        int idx = base + c;
        if (idx < n) rowptr[idx] = excl;
        excl += c4[c];
    }
}

__global__ void scatter_edges(const int* __restrict__ ei, const int* __restrict__ rowptr,
                              int* __restrict__ cursor, int* __restrict__ col, int e) {
    int i = blockIdx.x * blockDim.x + threadIdx.x;
    if (i >= e) return;
    int s = ei[i];
    int d = ei[NE + i];
    int p = atomicAdd(&cursor[d], 1);
    col[rowptr[d] + p] = s;
}

// ---------------- fp32 tiled GEMM:  C[M x 64] = op(A)[M x K] * B[64 x K]^T + bias ----------------
// block: 256 threads, 128-row x 64-col output tile; per-thread 8x4; K-chunks of 32.
// rowscale (optional): C row r multiplied by rowscale[r] after bias.

template <int K, bool RELU>
__global__ __launch_bounds__(256) void gemm_nt(const float* __restrict__ A,
                                               const float* __restrict__ B,
                                               const float* __restrict__ bias,
                                               const float* __restrict__ rowscale,
                                               float* __restrict__ C, int M) {
    __shared__ float aT[32][132];   // [k][row] padded
    __shared__ float bT[32][68];    // [k][col] padded
    int t = threadIdx.x;
    int row0 = blockIdx.x * 128;
    int nq = t & 15;        // row group 0..15
    int jq = t >> 4;        // col group 0..15
    float acc[8][4];
#pragma unroll
    for (int i = 0; i < 8; i++)
#pragma unroll
        for (int c = 0; c < 4; c++) acc[i][c] = 0.f;

    for (int k0 = 0; k0 < K; k0 += 32) {
        // stage A chunk: 128 rows x 32 cols = 1024 float4
#pragma unroll
        for (int i = 0; i < 4; i++) {
            int id = t + i * 256;
            int n = id >> 3, kc = id & 7;
            int row = row0 + n;
            float4 v = make_float4(0.f, 0.f, 0.f, 0.f);
            if (row < M) v = *(const float4*)&A[(size_t)row * K + k0 + kc * 4];
            if (RELU) {
                v.x = fmaxf(v.x, 0.f); v.y = fmaxf(v.y, 0.f);
                v.z = fmaxf(v.z, 0.f); v.w = fmaxf(v.w, 0.f);
            }
            aT[kc * 4 + 0][n] = v.x; aT[kc * 4 + 1][n] = v.y;
            aT[kc * 4 + 2][n] = v.z; aT[kc * 4 + 3][n] = v.w;
        }
        // stage B chunk: 64 rows x 32 cols = 512 float4
#pragma unroll
        for (int i = 0; i < 2; i++) {
            int id = t + i * 256;
            int j = id >> 3, kc = id & 7;
            float4 v = *(const float4*)&B[(size_t)j * K + k0 + kc * 4];
            bT[kc * 4 + 0][j] = v.x; bT[kc * 4 + 1][j] = v.y;
            bT[kc * 4 + 2][j] = v.z; bT[kc * 4 + 3][j] = v.w;
        }
        __syncthreads();
#pragma unroll
        for (int k = 0; k < 32; k++) {
            float4 a0 = *(const float4*)&aT[k][nq * 4];
            float4 a1 = *(const float4*)&aT[k][nq * 4 + 64];
            float4 b  = *(const float4*)&bT[k][jq * 4];
            float av[8] = {a0.x, a0.y, a0.z, a0.w, a1.x, a1.y, a1.z, a1.w};
            float bv[4] = {b.x, b.y, b.z, b.w};
#pragma unroll
            for (int i = 0; i < 8; i++)
#pragma unroll
                for (int c = 0; c < 4; c++) acc[i][c] += av[i] * bv[c];
        }
        __syncthreads();
    }

    float4 b4 = *(const float4*)&bias[jq * 4];
#pragma unroll
    for (int i = 0; i < 8; i++) {
        int row = row0 + ((i < 4) ? (nq * 4 + i) : (64 + nq * 4 + (i - 4)));
        if (row < M) {
            float sc = rowscale ? rowscale[row] : 1.f;
            float4 o;
            o.x = (acc[i][0] + b4.x) * sc; o.y = (acc[i][1] + b4.y) * sc;
            o.z = (acc[i][2] + b4.z) * sc; o.w = (acc[i][3] + b4.w) * sc;
            *(float4*)&C[(size_t)row * 64 + jq * 4] = o;
        }
    }
}

// ---------------- APPNP propagation on g = dinv ⊙ h ----------------
// g_{t+1}[d] = (1-a)*dinv[d]^2 * (sum_{s in N(d)} g_t[s] + g_t[d]) + a*g0[d]
// FINAL: write h = g_{t+1} / dinv[d] instead.
// one wave per node, lane = feature; row gathers are 256B contiguous per wave.

template <bool FINAL>
__global__ __launch_bounds__(256) void appnp_prop(const float* __restrict__ gcur,
                                                  float* __restrict__ gnext,
                                                  const float* __restrict__ g0,
                                                  const float* __restrict__ dinv,
                                                  const int* __restrict__ rowptr,
                                                  const int* __restrict__ col) {
    int wid = (blockIdx.x * 256 + threadIdx.x) >> 6;   // node id
    int lane = threadIdx.x & 63;                       // feature
    if (wid >= NN) return;
    float di = dinv[wid];
    float g0v = g0[(size_t)wid * HDIM + lane];
    float sum = gcur[(size_t)wid * HDIM + lane];       // self-loop
    int e = rowptr[wid], end = rowptr[wid + 1];
    for (; e + 3 < end; e += 4) {
        int s0 = col[e], s1 = col[e + 1], s2 = col[e + 2], s3 = col[e + 3];
        float v0 = gcur[(size_t)s0 * HDIM + lane];
        float v1 = gcur[(size_t)s1 * HDIM + lane];
        float v2 = gcur[(size_t)s2 * HDIM + lane];
        float v3 = gcur[(size_t)s3 * HDIM + lane];
        sum += v0 + v1 + v2 + v3;
    }
    for (; e < end; ++e) sum += gcur[(size_t)col[e] * HDIM + lane];
    float g = (1.f - ALPHA) * di * di * sum + ALPHA * g0v;
    if (FINAL) g = g / di;   // h = g / dinv
    gnext[(size_t)wid * HDIM + lane] = g;
}

// ---------------- launch ----------------

extern "C" void kernel_launch(void* const* d_in, const int* in_sizes, int n_in,
                              void* d_out, int out_size, void* d_ws, size_t ws_size,
                              hipStream_t stream) {
    const float* x    = (const float*)d_in[0];
    const int*  ei    = (const int*)d_in[1];      // harness converts int64 -> int32
    const float* W_in = (const float*)d_in[2];
    const float* b_in = (const float*)d_in[3];
    const float* W_out= (const float*)d_in[4];
    const float* b_out= (const float*)d_in[5];
    float* out = (float*)d_out;

    char* ws = (char*)d_ws;
    size_t off = 0;
    auto alloc = [&](size_t bytes) -> void* {
        void* p = ws + off;
        off = (off + bytes + 255) & ~(size_t)255;
        return p;
    };
    int*   deg    = (int*)  alloc((size_t)NN * 4);
    int*   cursor = (int*)  alloc((size_t)NN * 4);
    int*   rowptr = (int*)  alloc((size_t)(NN + 1) * 4);
    float* dinv   = (float*)alloc((size_t)NN * 4);
    int*   bsums  = (int*)  alloc(1024);
    int*   col    = (int*)  alloc((size_t)NE * 4);
    float* g0     = (float*)alloc((size_t)NN * HDIM * 4);
    float* gA     = (float*)alloc((size_t)NN * HDIM * 4);

    const int nb = (NN + 1023) / 1024;   // 98

    init_nodes<<<(NN + 255) / 256, 256, 0, stream>>>(deg, cursor, NN);
    count_deg<<<(NE + 255) / 256, 256, 0, stream>>>(ei, deg, NE);
    calc_dinv<<<(NN + 255) / 256, 256, 0, stream>>>(deg, dinv, NN);
    scan_block_sums<<<nb, 256, 0, stream>>>(deg, bsums, NN);
    scan_bsums<<<1, 64, 0, stream>>>(bsums, nb, rowptr, NN);
    scan_write_rowptr<<<nb, 256, 0, stream>>>(deg, bsums, rowptr, NN);
    scatter_edges<<<(NE + 255) / 256, 256, 0, stream>>>(ei, rowptr, cursor, col, NE);

    // g0 = (x @ W_in^T + b_in) * dinv[row]
    gemm_nt<NFEAT, false><<<(NN + 127) / 128, 256, 0, stream>>>(x, W_in, b_in, dinv, g0, NN);

    // K=4 APPNP iterations on g; 4th writes h (unscaled) into d_out
    const int pgrid = (NN * HDIM) / 256;   // 25000
    appnp_prop<false><<<pgrid, 256, 0, stream>>>(g0, gA, g0, dinv, rowptr, col);
    appnp_prop<false><<<pgrid, 256, 0, stream>>>(gA, out, g0, dinv, rowptr, col);
    appnp_prop<false><<<pgrid, 256, 0, stream>>>(out, gA, g0, dinv, rowptr, col);
    appnp_prop<true ><<<pgrid, 256, 0, stream>>>(gA, out, g0, dinv, rowptr, col);

    // out = relu(h) @ W_out^T + b_out  (in-place: each block reads only its own rows)
    gemm_nt<HDIM, true><<<(NN + 127) / 128, 256, 0, stream>>>(out, W_out, b_out, nullptr, out, NN);
}

// Round 3
// 770.351 us; speedup vs baseline: 1.1395x; 1.1395x over previous
//
#include <hip/hip_runtime.h>
#include <hip/hip_fp16.h>

#define NN 100000
#define NE 3200000
#define NFEAT 256
#define HDIM 64
#define NCLASS 64
#define ALPHA 0.1f

// ---------------- CSR build ----------------

__global__ void init_nodes(int* __restrict__ deg, int* __restrict__ cursor, int n) {
    int i = blockIdx.x * blockDim.x + threadIdx.x;
    if (i < n) { deg[i] = 1; cursor[i] = 0; }   // deg starts at 1 for the self-loop
}

__global__ void count_deg(const int* __restrict__ ei, int* __restrict__ deg, int e) {
    int i = blockIdx.x * blockDim.x + threadIdx.x;
    if (i < e) atomicAdd(&deg[ei[NE + i]], 1);   // dst row
}

__global__ void calc_dinv(const int* __restrict__ deg, float* __restrict__ dinv, int n) {
    int i = blockIdx.x * blockDim.x + threadIdx.x;
    if (i < n) dinv[i] = rsqrtf((float)deg[i]);  // deg >= 1 always
}

// exclusive scan of cnt[i] = deg[i]-1 (edges only; self-loops are implicit)

__global__ void scan_block_sums(const int* __restrict__ deg, int* __restrict__ bsums, int n) {
    __shared__ int sm[256];
    int t = threadIdx.x;
    int base = blockIdx.x * 1024 + t * 4;
    int s = 0;
#pragma unroll
    for (int c = 0; c < 4; c++) { int idx = base + c; if (idx < n) s += deg[idx] - 1; }
    sm[t] = s; __syncthreads();
    for (int off = 128; off > 0; off >>= 1) {
        if (t < off) sm[t] += sm[t + off];
        __syncthreads();
    }
    if (t == 0) bsums[blockIdx.x] = sm[0];
}

__global__ void scan_bsums(int* __restrict__ bsums, int nb, int* __restrict__ rowptr, int n) {
    if (threadIdx.x == 0 && blockIdx.x == 0) {
        int run = 0;
        for (int i = 0; i < nb; i++) { int v = bsums[i]; bsums[i] = run; run += v; }
        rowptr[n] = run;   // == NE
    }
}

__global__ void scan_write_rowptr(const int* __restrict__ deg, const int* __restrict__ bsums,
                                  int* __restrict__ rowptr, int n) {
    __shared__ int sm[256];
    int t = threadIdx.x;
    int base = blockIdx.x * 1024 + t * 4;
    int c4[4];
    int s = 0;
#pragma unroll
    for (int c = 0; c < 4; c++) {
        int idx = base + c;
        c4[c] = (idx < n) ? deg[idx] - 1 : 0;
        s += c4[c];
    }
    sm[t] = s; __syncthreads();
    for (int off = 1; off < 256; off <<= 1) {
        int v = 0;
        if (t >= off) v = sm[t - off];
        __syncthreads();
        if (t >= off) sm[t] += v;
        __syncthreads();
    }
    int excl = sm[t] - s + bsums[blockIdx.x];
#pragma unroll
    for (int c = 0; c < 4; c++) {
        int idx = base + c;
        if (idx < n) rowptr[idx] = excl;
        excl += c4[c];
    }
}

__global__ void scatter_edges(const int* __restrict__ ei, const int* __restrict__ rowptr,
                              int* __restrict__ cursor, int* __restrict__ col, int e) {
    int i = blockIdx.x * blockDim.x + threadIdx.x;
    if (i >= e) return;
    int s = ei[i];
    int d = ei[NE + i];
    int p = atomicAdd(&cursor[d], 1);
    __builtin_nontemporal_store(s, &col[rowptr[d] + p]);
}

// ---------------- fp32 tiled GEMM:  C[M x 64] = op(A)[M x K] * B[64 x K]^T + bias ----------------
// block: 256 threads, 128-row x 64-col output tile; per-thread 8x4; K-chunks of 32.
// rowscale (optional): row r scaled after bias. OUTHALF: C is __half.

template <int K, bool RELU, bool OUTHALF>
__global__ __launch_bounds__(256) void gemm_nt(const float* __restrict__ A,
                                               const float* __restrict__ B,
                                               const float* __restrict__ bias,
                                               const float* __restrict__ rowscale,
                                               void* __restrict__ Cv, int M) {
    __shared__ float aT[32][132];   // [k][row] padded
    __shared__ float bT[32][68];    // [k][col] padded
    int t = threadIdx.x;
    int row0 = blockIdx.x * 128;
    int nq = t & 15;        // row group 0..15
    int jq = t >> 4;        // col group 0..15
    float acc[8][4];
#pragma unroll
    for (int i = 0; i < 8; i++)
#pragma unroll
        for (int c = 0; c < 4; c++) acc[i][c] = 0.f;

    for (int k0 = 0; k0 < K; k0 += 32) {
#pragma unroll
        for (int i = 0; i < 4; i++) {
            int id = t + i * 256;
            int n = id >> 3, kc = id & 7;
            int row = row0 + n;
            float4 v = make_float4(0.f, 0.f, 0.f, 0.f);
            if (row < M) v = *(const float4*)&A[(size_t)row * K + k0 + kc * 4];
            if (RELU) {
                v.x = fmaxf(v.x, 0.f); v.y = fmaxf(v.y, 0.f);
                v.z = fmaxf(v.z, 0.f); v.w = fmaxf(v.w, 0.f);
            }
            aT[kc * 4 + 0][n] = v.x; aT[kc * 4 + 1][n] = v.y;
            aT[kc * 4 + 2][n] = v.z; aT[kc * 4 + 3][n] = v.w;
        }
#pragma unroll
        for (int i = 0; i < 2; i++) {
            int id = t + i * 256;
            int j = id >> 3, kc = id & 7;
            float4 v = *(const float4*)&B[(size_t)j * K + k0 + kc * 4];
            bT[kc * 4 + 0][j] = v.x; bT[kc * 4 + 1][j] = v.y;
            bT[kc * 4 + 2][j] = v.z; bT[kc * 4 + 3][j] = v.w;
        }
        __syncthreads();
#pragma unroll
        for (int k = 0; k < 32; k++) {
            float4 a0 = *(const float4*)&aT[k][nq * 4];
            float4 a1 = *(const float4*)&aT[k][nq * 4 + 64];
            float4 b  = *(const float4*)&bT[k][jq * 4];
            float av[8] = {a0.x, a0.y, a0.z, a0.w, a1.x, a1.y, a1.z, a1.w};
            float bv[4] = {b.x, b.y, b.z, b.w};
#pragma unroll
            for (int i = 0; i < 8; i++)
#pragma unroll
                for (int c = 0; c < 4; c++) acc[i][c] += av[i] * bv[c];
        }
        __syncthreads();
    }

    float4 b4 = *(const float4*)&bias[jq * 4];
#pragma unroll
    for (int i = 0; i < 8; i++) {
        int row = row0 + ((i < 4) ? (nq * 4 + i) : (64 + nq * 4 + (i - 4)));
        if (row < M) {
            float sc = rowscale ? rowscale[row] : 1.f;
            float4 o;
            o.x = (acc[i][0] + b4.x) * sc; o.y = (acc[i][1] + b4.y) * sc;
            o.z = (acc[i][2] + b4.z) * sc; o.w = (acc[i][3] + b4.w) * sc;
            if (OUTHALF) {
                __half2 lo = __floats2half2_rn(o.x, o.y);
                __half2 hi = __floats2half2_rn(o.z, o.w);
                uint2 u = make_uint2(*(unsigned*)&lo, *(unsigned*)&hi);
                *(uint2*)&((__half*)Cv)[(size_t)row * 64 + jq * 4] = u;
            } else {
                *(float4*)&((float*)Cv)[(size_t)row * 64 + jq * 4] = o;
            }
        }
    }
}

// ---------------- APPNP propagation on g = dinv ⊙ h, fp16 state ----------------
// g_{t+1}[d] = (1-a)*dinv[d]^2 * (sum_{s in N(d)} g_t[s] + g_t[d]) + a*g0[d]
// one wave per node; wave halves process two edges at once (lane>>5 selects edge,
// lane&31 selects half2 feature pair -> 128B coalesced row gather per edge).

template <bool FINAL>
__global__ __launch_bounds__(256) void appnp_prop_h(const __half* __restrict__ gcur,
                                                    void* __restrict__ gnext,
                                                    const __half* __restrict__ g0,
                                                    const float* __restrict__ dinv,
                                                    const int* __restrict__ rowptr,
                                                    const int* __restrict__ col) {
    int wid = (blockIdx.x * 256 + threadIdx.x) >> 6;   // node id
    int lane = threadIdx.x & 63;
    if (wid >= NN) return;
    int sub = lane >> 5;      // which edge of the pair
    int fl = lane & 31;       // feature-pair index (features 2*fl, 2*fl+1)
    const __half2* gc2 = (const __half2*)gcur;

    float ax = 0.f, ay = 0.f;
    int e = rowptr[wid], end = rowptr[wid + 1];
    int p = e + sub;
    for (; p + 6 < end; p += 8) {   // 8 edges per wave iteration (4 per half)
        int s0 = col[p], s1 = col[p + 2], s2 = col[p + 4], s3 = col[p + 6];
        float2 f0 = __half22float2(gc2[(size_t)s0 * 32 + fl]);
        float2 f1 = __half22float2(gc2[(size_t)s1 * 32 + fl]);
        float2 f2 = __half22float2(gc2[(size_t)s2 * 32 + fl]);
        float2 f3 = __half22float2(gc2[(size_t)s3 * 32 + fl]);
        ax += (f0.x + f1.x) + (f2.x + f3.x);
        ay += (f0.y + f1.y) + (f2.y + f3.y);
    }
    for (; p < end; p += 2) {
        float2 f = __half22float2(gc2[(size_t)col[p] * 32 + fl]);
        ax += f.x; ay += f.y;
    }
    // combine the two 32-lane halves (sum is symmetric -> every lane gets total)
    ax += __shfl(ax, lane ^ 32);
    ay += __shfl(ay, lane ^ 32);

    float di = dinv[wid];
    float2 self = __half22float2(gc2[(size_t)wid * 32 + fl]);
    float2 g0v  = __half22float2(((const __half2*)g0)[(size_t)wid * 32 + fl]);
    float k = (1.f - ALPHA) * di * di;
    float gx = k * (ax + self.x) + ALPHA * g0v.x;
    float gy = k * (ay + self.y) + ALPHA * g0v.y;

    if (lane < 32) {
        if (FINAL) {   // h = g / dinv, fp32
            float inv = 1.f / di;
            *(float2*)&((float*)gnext)[(size_t)wid * 64 + fl * 2] = make_float2(gx * inv, gy * inv);
        } else {
            ((__half2*)gnext)[(size_t)wid * 32 + fl] = __floats2half2_rn(gx, gy);
        }
    }
}

// ---------------- launch ----------------

extern "C" void kernel_launch(void* const* d_in, const int* in_sizes, int n_in,
                              void* d_out, int out_size, void* d_ws, size_t ws_size,
                              hipStream_t stream) {
    const float* x    = (const float*)d_in[0];
    const int*  ei    = (const int*)d_in[1];      // harness converts int64 -> int32
    const float* W_in = (const float*)d_in[2];
    const float* b_in = (const float*)d_in[3];
    const float* W_out= (const float*)d_in[4];
    const float* b_out= (const float*)d_in[5];
    float* out = (float*)d_out;

    char* ws = (char*)d_ws;
    size_t off = 0;
    auto alloc = [&](size_t bytes) -> void* {
        void* p = ws + off;
        off = (off + bytes + 255) & ~(size_t)255;
        return p;
    };
    int*    deg    = (int*)   alloc((size_t)NN * 4);
    int*    cursor = (int*)   alloc((size_t)NN * 4);
    int*    rowptr = (int*)   alloc((size_t)(NN + 1) * 4);
    float*  dinv   = (float*) alloc((size_t)NN * 4);
    int*    bsums  = (int*)   alloc(1024);
    int*    col    = (int*)   alloc((size_t)NE * 4);
    __half* g0h    = (__half*)alloc((size_t)NN * HDIM * 2);
    __half* gA     = (__half*)alloc((size_t)NN * HDIM * 2);
    __half* gB     = (__half*)alloc((size_t)NN * HDIM * 2);

    const int nb = (NN + 1023) / 1024;   // 98

    init_nodes<<<(NN + 255) / 256, 256, 0, stream>>>(deg, cursor, NN);
    count_deg<<<(NE + 255) / 256, 256, 0, stream>>>(ei, deg, NE);
    calc_dinv<<<(NN + 255) / 256, 256, 0, stream>>>(deg, dinv, NN);
    scan_block_sums<<<nb, 256, 0, stream>>>(deg, bsums, NN);
    scan_bsums<<<1, 64, 0, stream>>>(bsums, nb, rowptr, NN);
    scan_write_rowptr<<<nb, 256, 0, stream>>>(deg, bsums, rowptr, NN);
    scatter_edges<<<(NE + 255) / 256, 256, 0, stream>>>(ei, rowptr, cursor, col, NE);

    // g0 = (x @ W_in^T + b_in) * dinv[row], stored fp16
    gemm_nt<NFEAT, false, true><<<(NN + 127) / 128, 256, 0, stream>>>(x, W_in, b_in, dinv, g0h, NN);

    // K=4 APPNP iterations on g (fp16 state); 4th writes h (unscaled, fp32) into d_out
    const int pgrid = (NN * HDIM) / 256;   // 25000 blocks, 1 wave per node
    appnp_prop_h<false><<<pgrid, 256, 0, stream>>>(g0h, gA, g0h, dinv, rowptr, col);
    appnp_prop_h<false><<<pgrid, 256, 0, stream>>>(gA, gB, g0h, dinv, rowptr, col);
    appnp_prop_h<false><<<pgrid, 256, 0, stream>>>(gB, gA, g0h, dinv, rowptr, col);
    appnp_prop_h<true ><<<pgrid, 256, 0, stream>>>(gA, out, g0h, dinv, rowptr, col);

    // out = relu(h) @ W_out^T + b_out  (in-place: each block reads only its own rows)
    gemm_nt<HDIM, true, false><<<(NN + 127) / 128, 256, 0, stream>>>(out, W_out, b_out, nullptr, out, NN);
}

// Round 4
// 645.558 us; speedup vs baseline: 1.3597x; 1.1933x over previous
//
#include <hip/hip_runtime.h>
#include <hip/hip_fp16.h>

#define NN 100000
#define NE 3200000
#define NFEAT 256
#define HDIM 64
#define NCLASS 64
#define ALPHA 0.1f
#define NSLICE 8
#define SLICE_SZ (NN / NSLICE)   // 12500

// ---------------- CSR build ----------------

__global__ void init_deg(int* __restrict__ deg, int n) {
    int i = blockIdx.x * blockDim.x + threadIdx.x;
    if (i < n) deg[i] = 0;       // edge count only; self-loop handled in dinv/prop
}

// count degree AND record each edge's rank within its dst row (atomicAdd return)
__global__ void count_rank(const int* __restrict__ ei, int* __restrict__ deg,
                           int* __restrict__ erank, int e) {
    int i = blockIdx.x * blockDim.x + threadIdx.x;
    if (i < e) erank[i] = atomicAdd(&deg[ei[NE + i]], 1);
}

__global__ void calc_dinv(const int* __restrict__ deg, float* __restrict__ dinv, int n) {
    int i = blockIdx.x * blockDim.x + threadIdx.x;
    if (i < n) dinv[i] = rsqrtf((float)(deg[i] + 1));   // +1 for self-loop
}

// exclusive scan of deg (edge slots only)

__global__ void scan_block_sums(const int* __restrict__ deg, int* __restrict__ bsums, int n) {
    __shared__ int sm[256];
    int t = threadIdx.x;
    int base = blockIdx.x * 1024 + t * 4;
    int s = 0;
#pragma unroll
    for (int c = 0; c < 4; c++) { int idx = base + c; if (idx < n) s += deg[idx]; }
    sm[t] = s; __syncthreads();
    for (int off = 128; off > 0; off >>= 1) {
        if (t < off) sm[t] += sm[t + off];
        __syncthreads();
    }
    if (t == 0) bsums[blockIdx.x] = sm[0];
}

__global__ void scan_bsums(int* __restrict__ bsums, int nb, int* __restrict__ rowptr, int n) {
    if (threadIdx.x == 0 && blockIdx.x == 0) {
        int run = 0;
        for (int i = 0; i < nb; i++) { int v = bsums[i]; bsums[i] = run; run += v; }
        rowptr[n] = run;   // == NE
    }
}

__global__ void scan_write_rowptr(const int* __restrict__ deg, const int* __restrict__ bsums,
                                  int* __restrict__ rowptr, int n) {
    __shared__ int sm[256];
    int t = threadIdx.x;
    int base = blockIdx.x * 1024 + t * 4;
    int c4[4];
    int s = 0;
#pragma unroll
    for (int c = 0; c < 4; c++) {
        int idx = base + c;
        c4[c] = (idx < n) ? deg[idx] : 0;
        s += c4[c];
    }
    sm[t] = s; __syncthreads();
    for (int off = 1; off < 256; off <<= 1) {
        int v = 0;
        if (t >= off) v = sm[t - off];
        __syncthreads();
        if (t >= off) sm[t] += v;
        __syncthreads();
    }
    int excl = sm[t] - s + bsums[blockIdx.x];
#pragma unroll
    for (int c = 0; c < 4; c++) {
        int idx = base + c;
        if (idx < n) rowptr[idx] = excl;
        excl += c4[c];
    }
}

// scatter with no atomics; 8 dst-slices so each XCD's col writes stay in its L2
__global__ __launch_bounds__(256) void scatter_sliced(const int* __restrict__ ei,
                                                      const int* __restrict__ rowptr,
                                                      const int* __restrict__ erank,
                                                      int* __restrict__ col) {
    int s = blockIdx.x & (NSLICE - 1);
    int gid = (blockIdx.x >> 3) * 256 + threadIdx.x;
    const int stride = (gridDim.x >> 3) * 256;
    for (int e = gid; e < NE; e += stride) {
        unsigned d = (unsigned)ei[NE + e];
        if (d / SLICE_SZ == (unsigned)s) {
            col[rowptr[d] + erank[e]] = ei[e];
        }
    }
}

// ---------------- fp32 tiled GEMM:  C[M x 64] = op(A)[M x K] * B[64 x K]^T + bias ----------------

template <int K, bool RELU, bool OUTHALF>
__global__ __launch_bounds__(256) void gemm_nt(const float* __restrict__ A,
                                               const float* __restrict__ B,
                                               const float* __restrict__ bias,
                                               const float* __restrict__ rowscale,
                                               void* __restrict__ Cv, int M) {
    __shared__ float aT[32][132];   // [k][row] padded
    __shared__ float bT[32][68];    // [k][col] padded
    int t = threadIdx.x;
    int row0 = blockIdx.x * 128;
    int nq = t & 15;        // row group 0..15
    int jq = t >> 4;        // col group 0..15
    float acc[8][4];
#pragma unroll
    for (int i = 0; i < 8; i++)
#pragma unroll
        for (int c = 0; c < 4; c++) acc[i][c] = 0.f;

    for (int k0 = 0; k0 < K; k0 += 32) {
#pragma unroll
        for (int i = 0; i < 4; i++) {
            int id = t + i * 256;
            int n = id >> 3, kc = id & 7;
            int row = row0 + n;
            float4 v = make_float4(0.f, 0.f, 0.f, 0.f);
            if (row < M) v = *(const float4*)&A[(size_t)row * K + k0 + kc * 4];
            if (RELU) {
                v.x = fmaxf(v.x, 0.f); v.y = fmaxf(v.y, 0.f);
                v.z = fmaxf(v.z, 0.f); v.w = fmaxf(v.w, 0.f);
            }
            aT[kc * 4 + 0][n] = v.x; aT[kc * 4 + 1][n] = v.y;
            aT[kc * 4 + 2][n] = v.z; aT[kc * 4 + 3][n] = v.w;
        }
#pragma unroll
        for (int i = 0; i < 2; i++) {
            int id = t + i * 256;
            int j = id >> 3, kc = id & 7;
            float4 v = *(const float4*)&B[(size_t)j * K + k0 + kc * 4];
            bT[kc * 4 + 0][j] = v.x; bT[kc * 4 + 1][j] = v.y;
            bT[kc * 4 + 2][j] = v.z; bT[kc * 4 + 3][j] = v.w;
        }
        __syncthreads();
#pragma unroll
        for (int k = 0; k < 32; k++) {
            float4 a0 = *(const float4*)&aT[k][nq * 4];
            float4 a1 = *(const float4*)&aT[k][nq * 4 + 64];
            float4 b  = *(const float4*)&bT[k][jq * 4];
            float av[8] = {a0.x, a0.y, a0.z, a0.w, a1.x, a1.y, a1.z, a1.w};
            float bv[4] = {b.x, b.y, b.z, b.w};
#pragma unroll
            for (int i = 0; i < 8; i++)
#pragma unroll
                for (int c = 0; c < 4; c++) acc[i][c] += av[i] * bv[c];
        }
        __syncthreads();
    }

    float4 b4 = *(const float4*)&bias[jq * 4];
#pragma unroll
    for (int i = 0; i < 8; i++) {
        int row = row0 + ((i < 4) ? (nq * 4 + i) : (64 + nq * 4 + (i - 4)));
        if (row < M) {
            float sc = rowscale ? rowscale[row] : 1.f;
            float4 o;
            o.x = (acc[i][0] + b4.x) * sc; o.y = (acc[i][1] + b4.y) * sc;
            o.z = (acc[i][2] + b4.z) * sc; o.w = (acc[i][3] + b4.w) * sc;
            if (OUTHALF) {
                __half2 lo = __floats2half2_rn(o.x, o.y);
                __half2 hi = __floats2half2_rn(o.z, o.w);
                uint2 u = make_uint2(*(unsigned*)&lo, *(unsigned*)&hi);
                *(uint2*)&((__half*)Cv)[(size_t)row * 64 + jq * 4] = u;
            } else {
                *(float4*)&((float*)Cv)[(size_t)row * 64 + jq * 4] = o;
            }
        }
    }
}

// ---------------- APPNP propagation on g = dinv ⊙ h, fp16 state ----------------

template <bool FINAL>
__global__ __launch_bounds__(256) void appnp_prop_h(const __half* __restrict__ gcur,
                                                    void* __restrict__ gnext,
                                                    const __half* __restrict__ g0,
                                                    const float* __restrict__ dinv,
                                                    const int* __restrict__ rowptr,
                                                    const int* __restrict__ col) {
    int wid = (blockIdx.x * 256 + threadIdx.x) >> 6;   // node id
    int lane = threadIdx.x & 63;
    if (wid >= NN) return;
    int sub = lane >> 5;      // which edge of the pair
    int fl = lane & 31;       // feature-pair index
    const __half2* gc2 = (const __half2*)gcur;

    float ax = 0.f, ay = 0.f;
    int e = rowptr[wid], end = rowptr[wid + 1];
    int p = e + sub;
    for (; p + 6 < end; p += 8) {
        int s0 = col[p], s1 = col[p + 2], s2 = col[p + 4], s3 = col[p + 6];
        float2 f0 = __half22float2(gc2[(size_t)s0 * 32 + fl]);
        float2 f1 = __half22float2(gc2[(size_t)s1 * 32 + fl]);
        float2 f2 = __half22float2(gc2[(size_t)s2 * 32 + fl]);
        float2 f3 = __half22float2(gc2[(size_t)s3 * 32 + fl]);
        ax += (f0.x + f1.x) + (f2.x + f3.x);
        ay += (f0.y + f1.y) + (f2.y + f3.y);
    }
    for (; p < end; p += 2) {
        float2 f = __half22float2(gc2[(size_t)col[p] * 32 + fl]);
        ax += f.x; ay += f.y;
    }
    ax += __shfl(ax, lane ^ 32);
    ay += __shfl(ay, lane ^ 32);

    float di = dinv[wid];
    float2 self = __half22float2(gc2[(size_t)wid * 32 + fl]);
    float2 g0v  = __half22float2(((const __half2*)g0)[(size_t)wid * 32 + fl]);
    float k = (1.f - ALPHA) * di * di;
    float gx = k * (ax + self.x) + ALPHA * g0v.x;
    float gy = k * (ay + self.y) + ALPHA * g0v.y;

    if (lane < 32) {
        if (FINAL) {
            float inv = 1.f / di;
            *(float2*)&((float*)gnext)[(size_t)wid * 64 + fl * 2] = make_float2(gx * inv, gy * inv);
        } else {
            ((__half2*)gnext)[(size_t)wid * 32 + fl] = __floats2half2_rn(gx, gy);
        }
    }
}

// ---------------- launch ----------------

extern "C" void kernel_launch(void* const* d_in, const int* in_sizes, int n_in,
                              void* d_out, int out_size, void* d_ws, size_t ws_size,
                              hipStream_t stream) {
    const float* x    = (const float*)d_in[0];
    const int*  ei    = (const int*)d_in[1];      // harness converts int64 -> int32
    const float* W_in = (const float*)d_in[2];
    const float* b_in = (const float*)d_in[3];
    const float* W_out= (const float*)d_in[4];
    const float* b_out= (const float*)d_in[5];
    float* out = (float*)d_out;

    char* ws = (char*)d_ws;
    size_t off = 0;
    auto alloc = [&](size_t bytes) -> void* {
        void* p = ws + off;
        off = (off + bytes + 255) & ~(size_t)255;
        return p;
    };
    int*    deg    = (int*)   alloc((size_t)NN * 4);
    int*    rowptr = (int*)   alloc((size_t)(NN + 1) * 4);
    float*  dinv   = (float*) alloc((size_t)NN * 4);
    int*    bsums  = (int*)   alloc(1024);
    int*    col    = (int*)   alloc((size_t)NE * 4);
    int*    erank  = (int*)   alloc((size_t)NE * 4);
    __half* g0h    = (__half*)alloc((size_t)NN * HDIM * 2);
    __half* gA     = (__half*)alloc((size_t)NN * HDIM * 2);
    __half* gB     = (__half*)alloc((size_t)NN * HDIM * 2);

    const int nb = (NN + 1023) / 1024;   // 98

    init_deg<<<(NN + 255) / 256, 256, 0, stream>>>(deg, NN);
    count_rank<<<(NE + 255) / 256, 256, 0, stream>>>(ei, deg, erank, NE);
    calc_dinv<<<(NN + 255) / 256, 256, 0, stream>>>(deg, dinv, NN);
    scan_block_sums<<<nb, 256, 0, stream>>>(deg, bsums, NN);
    scan_bsums<<<1, 64, 0, stream>>>(bsums, nb, rowptr, NN);
    scan_write_rowptr<<<nb, 256, 0, stream>>>(deg, bsums, rowptr, NN);
    scatter_sliced<<<2048, 256, 0, stream>>>(ei, rowptr, erank, col);

    // g0 = (x @ W_in^T + b_in) * dinv[row], stored fp16
    gemm_nt<NFEAT, false, true><<<(NN + 127) / 128, 256, 0, stream>>>(x, W_in, b_in, dinv, g0h, NN);

    // K=4 APPNP iterations on g (fp16 state); 4th writes h (unscaled, fp32) into d_out
    const int pgrid = (NN * HDIM) / 256;   // 25000 blocks, 1 wave per node
    appnp_prop_h<false><<<pgrid, 256, 0, stream>>>(g0h, gA, g0h, dinv, rowptr, col);
    appnp_prop_h<false><<<pgrid, 256, 0, stream>>>(gA, gB, g0h, dinv, rowptr, col);
    appnp_prop_h<false><<<pgrid, 256, 0, stream>>>(gB, gA, g0h, dinv, rowptr, col);
    appnp_prop_h<true ><<<pgrid, 256, 0, stream>>>(gA, out, g0h, dinv, rowptr, col);

    // out = relu(h) @ W_out^T + b_out  (in-place: each block reads only its own rows)
    gemm_nt<HDIM, true, false><<<(NN + 127) / 128, 256, 0, stream>>>(out, W_out, b_out, nullptr, out, NN);
}